// Round 10
// baseline (2018.440 us; speedup 1.0000x reference)
//
#include <hip/hip_runtime.h>
#include <hip/hip_bf16.h>
#include <math.h>

// Problem constants (from reference)
constexpr int N = 100000;    // nodes
constexpr int E = 3200000;   // edges
constexpr int FIN = 128, H1 = 64, H2 = 32, COUT = 2;

// Bucketing: 64 dst-nodes per bucket, fixed-capacity slices
constexpr int BUK_SHIFT = 6;
constexpr int BUK_NODES = 64;                          // 1 << BUK_SHIFT
constexpr int NBUK = (N + BUK_NODES - 1) / BUK_NODES;  // 1563
constexpr int CAP = 2560;             // slice capacity; mean fill 2048, sigma~45
// src segmentation for temporal L2 locality: seg = src >> 13 (8192 rows = 1 MB of y1)
constexpr int SEG_SHIFT = 13;
constexpr int NSEG = (N >> SEG_SHIFT) + 1;             // 13

constexpr int MS_TPB = 1024;
constexpr int MS_EPT = 24;                             // edges per thread
constexpr int CHUNK = MS_TPB * MS_EPT;                 // 24576
constexpr int MS_WGS = (E + CHUNK - 1) / CHUNK;        // 131

// ---------------- init: gcursor[b] = b*CAP ----------------
__global__ void k_initcur(int* __restrict__ gcursor) {
    int i = blockIdx.x * blockDim.x + threadIdx.x;
    if (i < NBUK) gcursor[i] = i * CAP;
}

// ---------------- multisplit into fixed-capacity bucket slices ----------------
// packed entry: src (17 bits) | local_node (6 bits) << 17
__global__ __launch_bounds__(MS_TPB)
void k_mslice(const int* __restrict__ src, const int* __restrict__ dst,
              int* __restrict__ gcursor, unsigned* __restrict__ ebuf) {
    __shared__ int cnt[NBUK];
    __shared__ int base[NBUK];
    const int t = threadIdx.x;
    for (int i = t; i < NBUK; i += MS_TPB) cnt[i] = 0;
    __syncthreads();
    const int e0 = blockIdx.x * CHUNK;

    int rb[MS_EPT];
    unsigned rv[MS_EPT];
#pragma unroll
    for (int j = 0; j < MS_EPT; ++j) {
        int e = e0 + j * MS_TPB + t;
        if (e < E) {
            int d = dst[e];
            int b = d >> BUK_SHIFT;
            rb[j] = b;
            rv[j] = (unsigned)src[e] | ((unsigned)(d & (BUK_NODES - 1)) << 17);
            atomicAdd(&cnt[b], 1);
        } else {
            rb[j] = -1; rv[j] = 0;
        }
    }
    __syncthreads();
    for (int i = t; i < NBUK; i += MS_TPB) {
        int c = cnt[i];
        base[i] = c ? atomicAdd(&gcursor[i], c) : 0;
    }
    __syncthreads();
    for (int i = t; i < NBUK; i += MS_TPB) cnt[i] = 0;
    __syncthreads();
#pragma unroll
    for (int j = 0; j < MS_EPT; ++j) {
        int b = rb[j];
        if (b >= 0) {
            int r = atomicAdd(&cnt[b], 1);
            int p = base[b] + r;
            if (p < (b + 1) * CAP) ebuf[p] = rv[j];   // overflow guard (statistically impossible)
        }
    }
}

// ---------------- per-bucket build: seg-sort slice in LDS + dinv ----------------
__global__ __launch_bounds__(256)
void k_build(const int* __restrict__ gcursor, unsigned* __restrict__ ebuf,
             float* __restrict__ dinv) {
    __shared__ unsigned ent[CAP];
    __shared__ int scnt[NSEG];
    __shared__ int sbase[NSEG];
    __shared__ int deg[BUK_NODES];
    const int b = blockIdx.x;
    const int t = threadIdx.x;
    int fill = gcursor[b] - b * CAP;
    if (fill > CAP) fill = CAP;
    const int gbase = b * CAP;

    if (t < NSEG) scnt[t] = 0;
    if (t < BUK_NODES) deg[t] = 0;
    __syncthreads();
    for (int j = t; j < fill; j += 256) {
        unsigned v = ebuf[gbase + j];
        ent[j] = v;
        atomicAdd(&scnt[(v & 0x1FFFFu) >> SEG_SHIFT], 1);
        atomicAdd(&deg[v >> 17], 1);
    }
    __syncthreads();
    if (t == 0) {
        int run = 0;
        for (int s = 0; s < NSEG; ++s) { sbase[s] = run; run += scnt[s]; }
    }
    if (t < BUK_NODES) {
        int node = (b << BUK_SHIFT) + t;
        if (node < N) dinv[node] = rsqrtf((float)deg[t] + 1.0f);  // self-loop included
    }
    __syncthreads();
    if (t < NSEG) scnt[t] = sbase[t];   // cursors
    __syncthreads();
    for (int j = t; j < fill; j += 256) {
        unsigned v = ent[j];
        int p = atomicAdd(&scnt[(v & 0x1FFFFu) >> SEG_SHIFT], 1);
        ebuf[gbase + p] = v;   // seg-major, random dst order within seg
    }
}

// ---------------- register-tiled GEMM + dinv scale, bf16 output ----------------
template<int FI, int FO>
__global__ __launch_bounds__(256)
void k_gemm_tile_bf(const float* __restrict__ h, const float* __restrict__ Wg,
                    const float* __restrict__ dinv, __hip_bfloat16* __restrict__ y) {
    constexpr int TX  = FO / 4;
    constexpr int TY  = 256 / TX;
    constexpr int RPT = 64 / TY;
    constexpr int XS  = 68;
    constexpr int KQ  = FI / 4;

    __shared__ float xsT[FI][XS];

    const int tid = threadIdx.x;
    const int tx = tid % TX;
    const int ty = tid / TX;
    const int row0 = blockIdx.x * 64;

    for (int idx = tid; idx < 64 * KQ; idx += 256) {
        int g   = idx / 8;
        int rlo = idx % 8;
        int k4  = g % KQ;
        int rhi = g / KQ;
        int r   = rlo + 8 * rhi;
        int row = row0 + r;
        float4 v = make_float4(0.f, 0.f, 0.f, 0.f);
        if (row < N) v = *(const float4*)(h + (size_t)row * FI + 4 * k4);
        xsT[4 * k4 + 0][r] = v.x;
        xsT[4 * k4 + 1][r] = v.y;
        xsT[4 * k4 + 2][r] = v.z;
        xsT[4 * k4 + 3][r] = v.w;
    }
    __syncthreads();

    float acc[RPT][4];
#pragma unroll
    for (int i = 0; i < RPT; ++i)
#pragma unroll
        for (int c = 0; c < 4; ++c) acc[i][c] = 0.0f;

#pragma unroll 4
    for (int k = 0; k < FI; ++k) {
        const float4 wv = *(const float4*)(Wg + (size_t)k * FO + 4 * tx);
        float xv[RPT];
        if constexpr (RPT == 4) {
            float4 t = *(const float4*)&xsT[k][4 * ty];
            xv[0] = t.x; xv[1] = t.y; xv[2] = t.z; xv[3] = t.w;
        } else {
            float2 t = *(const float2*)&xsT[k][2 * ty];
            xv[0] = t.x; xv[1] = t.y;
        }
#pragma unroll
        for (int i = 0; i < RPT; ++i) {
            acc[i][0] = fmaf(xv[i], wv.x, acc[i][0]);
            acc[i][1] = fmaf(xv[i], wv.y, acc[i][1]);
            acc[i][2] = fmaf(xv[i], wv.z, acc[i][2]);
            acc[i][3] = fmaf(xv[i], wv.w, acc[i][3]);
        }
    }

#pragma unroll
    for (int i = 0; i < RPT; ++i) {
        int row = row0 + ty * RPT + i;
        if (row >= N) continue;
        float di = dinv[row];
        auto cvt = [](float f) -> unsigned short {
            __hip_bfloat16 b = __float2bfloat16(f);
            return *reinterpret_cast<unsigned short*>(&b);
        };
        ushort4 pk;
        pk.x = cvt(di * acc[i][0]);
        pk.y = cvt(di * acc[i][1]);
        pk.z = cvt(di * acc[i][2]);
        pk.w = cvt(di * acc[i][3]);
        *(ushort4*)&y[(size_t)row * FO + 4 * tx] = pk;
    }
}

// ---------------- fused GEMM + dinv scale, fp32 output (layer 3, tiny) ----------------
template<int FI, int FO, int ROWS>
__global__ __launch_bounds__(FO * ROWS)
void k_gemm_scale(const float* __restrict__ h, const float* __restrict__ W,
                  const float* __restrict__ dinv, float* __restrict__ y) {
    __shared__ float xs[ROWS][FI];
    const int j = threadIdx.x;
    const int r = threadIdx.y;
    const int row0 = blockIdx.x * ROWS;
    const int tid = r * FO + j;
    constexpr int NT = FO * ROWS;
    for (int t = tid; t < ROWS * FI; t += NT) {
        int rr = t / FI, kk = t % FI;
        int row = row0 + rr;
        xs[rr][kk] = (row < N) ? h[(size_t)row * FI + kk] : 0.0f;
    }
    __syncthreads();
    const int row = row0 + r;
    if (row >= N) return;
    float acc = 0.0f;
#pragma unroll
    for (int k = 0; k < FI; ++k)
        acc = fmaf(xs[r][k], W[k * FO + j], acc);
    y[(size_t)row * FO + j] = dinv[row] * acc;
}

// ---------------- edge-parallel bucket aggregate: LDS fp32 acc tile ----------------
// One block per 64-node bucket. Edge list is seg-major sorted -> all co-resident
// blocks (entire grid fits: 1563 blocks @ 6/CU) sweep the same ~1 MB slice of y
// concurrently. Flat unroll-8 loop restores MLP; LDS atomic float adds accumulate.
template<int F>
__global__ __launch_bounds__(256, 6)
void k_agg(const int* __restrict__ gcursor, const unsigned* __restrict__ csr,
           const __hip_bfloat16* __restrict__ y, const float* __restrict__ dinv,
           const float* __restrict__ bias, float* __restrict__ out) {
    constexpr int LPE = F / 2;           // lanes (words) per edge row: 32 or 16
    constexpr int EPW = 64 / LPE;        // edges per wave: 2 or 4
    constexpr int STEP = 4 * EPW;        // edges per block per round (4 waves)
    __shared__ float accx[BUK_NODES][LPE];
    __shared__ float accy[BUK_NODES][LPE];

    const int b = blockIdx.x;
    const int t = threadIdx.x;
    for (int i = t; i < BUK_NODES * LPE; i += 256) {
        (&accx[0][0])[i] = 0.0f;
        (&accy[0][0])[i] = 0.0f;
    }
    __syncthreads();

    int fill = gcursor[b] - b * CAP;
    if (fill > CAP) fill = CAP;
    const int gbase = b * CAP;
    const unsigned* yw = (const unsigned*)y;

    const int l = t & 63;
    const int w = t >> 6;
    const int half = l / LPE;            // edge slot within wave
    const int fw = l % LPE;              // feature word

    int e = w * EPW + half;
    // unroll-8: 8 independent gathers in flight per lane
    for (; e + 7 * STEP < fill; e += 8 * STEP) {
        unsigned v[8], u[8];
#pragma unroll
        for (int k = 0; k < 8; ++k) v[k] = csr[gbase + e + k * STEP];
#pragma unroll
        for (int k = 0; k < 8; ++k) u[k] = yw[(size_t)(v[k] & 0x1FFFFu) * LPE + fw];
#pragma unroll
        for (int k = 0; k < 8; ++k) {
            int ld = (int)(v[k] >> 17);
            atomicAdd(&accx[ld][fw], __uint_as_float(u[k] << 16));
            atomicAdd(&accy[ld][fw], __uint_as_float(u[k] & 0xffff0000u));
        }
    }
    for (; e < fill; e += STEP) {
        unsigned v = csr[gbase + e];
        unsigned u = yw[(size_t)(v & 0x1FFFFu) * LPE + fw];
        int ld = (int)(v >> 17);
        atomicAdd(&accx[ld][fw], __uint_as_float(u << 16));
        atomicAdd(&accy[ld][fw], __uint_as_float(u & 0xffff0000u));
    }
    __syncthreads();

    // epilogue: self-loop + dinv + bias + relu, coalesced float2 stores
    const int base = b << BUK_SHIFT;
    for (int i = t; i < BUK_NODES * LPE; i += 256) {
        const int node = base + i / LPE;
        const int word = i % LPE;
        if (node >= N) continue;
        unsigned su = yw[(size_t)node * LPE + word];
        float sx = __uint_as_float(su << 16);
        float sy = __uint_as_float(su & 0xffff0000u);
        const float di = dinv[node];
        float o0 = fmaxf(fmaf(di, accx[i / LPE][word] + sx, bias[2 * word]), 0.0f);
        float o1 = fmaxf(fmaf(di, accy[i / LPE][word] + sy, bias[2 * word + 1]), 0.0f);
        float2 res; res.x = o0; res.y = o1;
        *(float2*)&out[(size_t)node * F + 2 * word] = res;
    }
}

// ---------------- layer 3: bucket aggregate + log_softmax (2 classes) ----------------
__global__ __launch_bounds__(256, 6)
void k_final(const int* __restrict__ gcursor, const unsigned* __restrict__ csr,
             const float* __restrict__ y, const float* __restrict__ dinv,
             const float* __restrict__ bias, float* __restrict__ out) {
    __shared__ float acc[BUK_NODES][2];
    const int b = blockIdx.x;
    const int t = threadIdx.x;
    if (t < BUK_NODES) { acc[t][0] = 0.0f; acc[t][1] = 0.0f; }
    __syncthreads();
    int fill = gcursor[b] - b * CAP;
    if (fill > CAP) fill = CAP;
    const int gbase = b * CAP;

    int j = t;
    for (; j + 3 * 256 < fill; j += 4 * 256) {
        unsigned v0 = csr[gbase + j], v1 = csr[gbase + j + 256];
        unsigned v2 = csr[gbase + j + 512], v3 = csr[gbase + j + 768];
        float2 a0 = *(const float2*)(y + 2 * (v0 & 0x1FFFFu));
        float2 a1 = *(const float2*)(y + 2 * (v1 & 0x1FFFFu));
        float2 a2 = *(const float2*)(y + 2 * (v2 & 0x1FFFFu));
        float2 a3 = *(const float2*)(y + 2 * (v3 & 0x1FFFFu));
        atomicAdd(&acc[v0 >> 17][0], a0.x); atomicAdd(&acc[v0 >> 17][1], a0.y);
        atomicAdd(&acc[v1 >> 17][0], a1.x); atomicAdd(&acc[v1 >> 17][1], a1.y);
        atomicAdd(&acc[v2 >> 17][0], a2.x); atomicAdd(&acc[v2 >> 17][1], a2.y);
        atomicAdd(&acc[v3 >> 17][0], a3.x); atomicAdd(&acc[v3 >> 17][1], a3.y);
    }
    for (; j < fill; j += 256) {
        unsigned v = csr[gbase + j];
        float2 a = *(const float2*)(y + 2 * (v & 0x1FFFFu));
        atomicAdd(&acc[v >> 17][0], a.x);
        atomicAdd(&acc[v >> 17][1], a.y);
    }
    __syncthreads();
    if (t < BUK_NODES) {
        const int node = (b << BUK_SHIFT) + t;
        if (node < N) {
            const float di = dinv[node];
            float z0 = fmaf(di, acc[t][0] + y[2 * node],     bias[0]);
            float z1 = fmaf(di, acc[t][1] + y[2 * node + 1], bias[1]);
            float m = fmaxf(z0, z1);
            float lse = m + logf(expf(z0 - m) + expf(z1 - m));
            float2 res; res.x = z0 - lse; res.y = z1 - lse;
            *(float2*)&out[2 * node] = res;
        }
    }
}

extern "C" void kernel_launch(void* const* d_in, const int* in_sizes, int n_in,
                              void* d_out, int out_size, void* d_ws, size_t ws_size,
                              hipStream_t stream) {
    const float* x   = (const float*)d_in[0];
    const int*   ei  = (const int*)d_in[1];
    const float* W1  = (const float*)d_in[2];
    const float* b1  = (const float*)d_in[3];
    const float* W2  = (const float*)d_in[4];
    const float* b2  = (const float*)d_in[5];
    const float* W3  = (const float*)d_in[6];
    const float* b3  = (const float*)d_in[7];
    float* out = (float*)d_out;

    const int* src = ei;
    const int* dst = ei + E;

    // workspace layout
    char* p = (char*)d_ws;
    float*    dinv    = (float*)p;    p += (size_t)N * 4;
    int*      gcursor = (int*)p;      p += (size_t)NBUK * 4;
    unsigned* ebuf    = (unsigned*)p; p += (size_t)NBUK * CAP * 4;    // 16 MB
    char*     bufA    = p;            p += (size_t)N * 64 * 4;        // 25.6 MB
    char*     bufB    = p;            p += (size_t)N * 64 * 4;        // 25.6 MB

    __hip_bfloat16* y1 = (__hip_bfloat16*)bufA;     // N*64*2 B
    float*          h1 = (float*)bufB;              // N*64*4 B
    __hip_bfloat16* y2 = (__hip_bfloat16*)bufA;     // N*32*2 B (y1 dead)
    float*          h2 = (float*)(bufA + (size_t)N * H2 * 2);  // N*32*4 B
    float*          y3 = (float*)bufB;              // N*2*4 B (h1 dead)

    // ---- edge structure build ----
    k_initcur<<<(NBUK + 255) / 256, 256, 0, stream>>>(gcursor);
    k_mslice <<<MS_WGS, MS_TPB, 0, stream>>>(src, dst, gcursor, ebuf);
    k_build  <<<NBUK, 256, 0, stream>>>(gcursor, ebuf, dinv);

    // ---- layer 1: 128 -> 64 ----
    k_gemm_tile_bf<FIN, H1><<<(N + 63) / 64, 256, 0, stream>>>(x, W1, dinv, y1);
    k_agg<H1><<<NBUK, 256, 0, stream>>>(gcursor, ebuf, y1, dinv, b1, h1);

    // ---- layer 2: 64 -> 32 ----
    k_gemm_tile_bf<H1, H2><<<(N + 63) / 64, 256, 0, stream>>>(h1, W2, dinv, y2);
    k_agg<H2><<<NBUK, 256, 0, stream>>>(gcursor, ebuf, y2, dinv, b2, h2);

    // ---- layer 3: 32 -> 2 + log_softmax ----
    k_gemm_scale<H2, COUT, 128><<<(N + 127) / 128, dim3(COUT, 128), 0, stream>>>(h2, W3, dinv, y3);
    k_final<<<NBUK, 256, 0, stream>>>(gcursor, ebuf, y3, dinv, b3, out);
}

// Round 11
// 712.945 us; speedup vs baseline: 2.8311x; 2.8311x over previous
//
#include <hip/hip_runtime.h>
#include <hip/hip_bf16.h>
#include <math.h>

// Problem constants (from reference)
constexpr int N = 100000;    // nodes
constexpr int E = 3200000;   // edges
constexpr int FIN = 128, H1 = 64, H2 = 32, COUT = 2;

// Bucketing: 64 dst-nodes per bucket, fixed-capacity slices
constexpr int BUK_SHIFT = 6;
constexpr int BUK_NODES = 64;                          // 1 << BUK_SHIFT
constexpr int NBUK = (N + BUK_NODES - 1) / BUK_NODES;  // 1563
constexpr int CAP = 2560;             // slice capacity; mean fill 2048, sigma~45
// src segmentation for temporal L2 locality: seg = src >> 14 (16384 rows = 2.1 MB of y1)
constexpr int SEG_SHIFT = 14;
constexpr int NSEG = 7;
constexpr int KEYS = NSEG * BUK_NODES;                 // 448
constexpr int RSTR = KEYS + 1;                         // rptr stride per bucket (449)

constexpr int MS_TPB = 1024;
constexpr int MS_EPT = 24;                             // edges per thread
constexpr int CHUNK = MS_TPB * MS_EPT;                 // 24576
constexpr int MS_WGS = (E + CHUNK - 1) / CHUNK;        // 131

// ---------------- init: gcursor[b] = b*CAP ----------------
__global__ void k_initcur(int* __restrict__ gcursor) {
    int i = blockIdx.x * blockDim.x + threadIdx.x;
    if (i < NBUK) gcursor[i] = i * CAP;
}

// ---------------- multisplit into fixed-capacity bucket slices ----------------
// packed entry: src (17 bits) | local_node (6 bits) << 17
__global__ __launch_bounds__(MS_TPB)
void k_mslice(const int* __restrict__ src, const int* __restrict__ dst,
              int* __restrict__ gcursor, unsigned* __restrict__ ebuf) {
    __shared__ int cnt[NBUK];
    __shared__ int base[NBUK];
    const int t = threadIdx.x;
    for (int i = t; i < NBUK; i += MS_TPB) cnt[i] = 0;
    __syncthreads();
    const int e0 = blockIdx.x * CHUNK;

    int rb[MS_EPT];
    unsigned rv[MS_EPT];
#pragma unroll
    for (int j = 0; j < MS_EPT; ++j) {
        int e = e0 + j * MS_TPB + t;
        if (e < E) {
            int d = dst[e];
            int b = d >> BUK_SHIFT;
            rb[j] = b;
            rv[j] = (unsigned)src[e] | ((unsigned)(d & (BUK_NODES - 1)) << 17);
            atomicAdd(&cnt[b], 1);
        } else {
            rb[j] = -1; rv[j] = 0;
        }
    }
    __syncthreads();
    for (int i = t; i < NBUK; i += MS_TPB) {
        int c = cnt[i];
        base[i] = c ? atomicAdd(&gcursor[i], c) : 0;
    }
    __syncthreads();
    for (int i = t; i < NBUK; i += MS_TPB) cnt[i] = 0;
    __syncthreads();
#pragma unroll
    for (int j = 0; j < MS_EPT; ++j) {
        int b = rb[j];
        if (b >= 0) {
            int r = atomicAdd(&cnt[b], 1);
            int p = base[b] + r;
            if (p < (b + 1) * CAP) ebuf[p] = rv[j];   // overflow guard (statistically impossible)
        }
    }
}

// ---------------- per-bucket build: counting-sort by (seg, local_dst) ----------------
__global__ __launch_bounds__(256)
void k_build(const int* __restrict__ gcursor, unsigned* __restrict__ ebuf,
             int* __restrict__ rptr, float* __restrict__ dinv) {
    __shared__ unsigned ent[CAP];
    __shared__ int cnt[512];
    __shared__ int sa[512];
    __shared__ int sb[512];
    __shared__ int cur[512];
    const int b = blockIdx.x;
    const int t = threadIdx.x;
    int fill = gcursor[b] - b * CAP;
    if (fill > CAP) fill = CAP;
    const int gbase = b * CAP;

    cnt[t] = 0; cnt[t + 256] = 0;
    __syncthreads();
    for (int j = t; j < fill; j += 256) {
        unsigned v = ebuf[gbase + j];
        ent[j] = v;
        int key = (int)((v & 0x1FFFFu) >> SEG_SHIFT) * BUK_NODES + (int)(v >> 17);
        atomicAdd(&cnt[key], 1);
    }
    __syncthreads();
    sa[t] = cnt[t]; sa[t + 256] = cnt[t + 256];
    __syncthreads();
    int* pin = sa; int* pout = sb;
    for (int off = 1; off < 512; off <<= 1) {
        pout[t]       = pin[t]       + ((t >= off)       ? pin[t - off]       : 0);
        pout[t + 256] = pin[t + 256] + ((t + 256 >= off) ? pin[t + 256 - off] : 0);
        __syncthreads();
        int* tmp = pin; pin = pout; pout = tmp;
    }
    {
        int ex0 = pin[t] - cnt[t];
        int ex1 = pin[t + 256] - cnt[t + 256];
        cur[t] = gbase + ex0;
        cur[t + 256] = gbase + ex1;
        if (t < KEYS) rptr[b * RSTR + t] = gbase + ex0;
        int k2 = t + 256;
        if (k2 < KEYS) rptr[b * RSTR + k2] = gbase + ex1;
        if (t == 0) rptr[b * RSTR + KEYS] = gbase + fill;   // sentinel
    }
    if (t < BUK_NODES) {
        int deg = 0;
#pragma unroll
        for (int s = 0; s < NSEG; ++s) deg += cnt[s * BUK_NODES + t];
        int node = (b << BUK_SHIFT) + t;
        if (node < N) dinv[node] = rsqrtf((float)deg + 1.0f);
    }
    __syncthreads();
    for (int j = t; j < fill; j += 256) {
        unsigned v = ent[j];
        int key = (int)((v & 0x1FFFFu) >> SEG_SHIFT) * BUK_NODES + (int)(v >> 17);
        int p = atomicAdd(&cur[key], 1);
        ebuf[p] = v & 0x1FFFFu;   // sorted, plain src
    }
}

// ---------------- register-tiled GEMM + dinv scale, bf16 output ----------------
template<int FI, int FO>
__global__ __launch_bounds__(256)
void k_gemm_tile_bf(const float* __restrict__ h, const float* __restrict__ Wg,
                    const float* __restrict__ dinv, __hip_bfloat16* __restrict__ y) {
    constexpr int TX  = FO / 4;
    constexpr int TY  = 256 / TX;
    constexpr int RPT = 64 / TY;
    constexpr int XS  = 68;
    constexpr int KQ  = FI / 4;

    __shared__ float xsT[FI][XS];

    const int tid = threadIdx.x;
    const int tx = tid % TX;
    const int ty = tid / TX;
    const int row0 = blockIdx.x * 64;

    for (int idx = tid; idx < 64 * KQ; idx += 256) {
        int g   = idx / 8;
        int rlo = idx % 8;
        int k4  = g % KQ;
        int rhi = g / KQ;
        int r   = rlo + 8 * rhi;
        int row = row0 + r;
        float4 v = make_float4(0.f, 0.f, 0.f, 0.f);
        if (row < N) v = *(const float4*)(h + (size_t)row * FI + 4 * k4);
        xsT[4 * k4 + 0][r] = v.x;
        xsT[4 * k4 + 1][r] = v.y;
        xsT[4 * k4 + 2][r] = v.z;
        xsT[4 * k4 + 3][r] = v.w;
    }
    __syncthreads();

    float acc[RPT][4];
#pragma unroll
    for (int i = 0; i < RPT; ++i)
#pragma unroll
        for (int c = 0; c < 4; ++c) acc[i][c] = 0.0f;

#pragma unroll 4
    for (int k = 0; k < FI; ++k) {
        const float4 wv = *(const float4*)(Wg + (size_t)k * FO + 4 * tx);
        float xv[RPT];
        if constexpr (RPT == 4) {
            float4 t = *(const float4*)&xsT[k][4 * ty];
            xv[0] = t.x; xv[1] = t.y; xv[2] = t.z; xv[3] = t.w;
        } else {
            float2 t = *(const float2*)&xsT[k][2 * ty];
            xv[0] = t.x; xv[1] = t.y;
        }
#pragma unroll
        for (int i = 0; i < RPT; ++i) {
            acc[i][0] = fmaf(xv[i], wv.x, acc[i][0]);
            acc[i][1] = fmaf(xv[i], wv.y, acc[i][1]);
            acc[i][2] = fmaf(xv[i], wv.z, acc[i][2]);
            acc[i][3] = fmaf(xv[i], wv.w, acc[i][3]);
        }
    }

#pragma unroll
    for (int i = 0; i < RPT; ++i) {
        int row = row0 + ty * RPT + i;
        if (row >= N) continue;
        float di = dinv[row];
        auto cvt = [](float f) -> unsigned short {
            __hip_bfloat16 b = __float2bfloat16(f);
            return *reinterpret_cast<unsigned short*>(&b);
        };
        ushort4 pk;
        pk.x = cvt(di * acc[i][0]);
        pk.y = cvt(di * acc[i][1]);
        pk.z = cvt(di * acc[i][2]);
        pk.w = cvt(di * acc[i][3]);
        *(ushort4*)&y[(size_t)row * FO + 4 * tx] = pk;
    }
}

// ---------------- fused GEMM + dinv scale, fp32 output (layer 3, tiny) ----------------
template<int FI, int FO, int ROWS>
__global__ __launch_bounds__(FO * ROWS)
void k_gemm_scale(const float* __restrict__ h, const float* __restrict__ W,
                  const float* __restrict__ dinv, float* __restrict__ y) {
    __shared__ float xs[ROWS][FI];
    const int j = threadIdx.x;
    const int r = threadIdx.y;
    const int row0 = blockIdx.x * ROWS;
    const int tid = r * FO + j;
    constexpr int NT = FO * ROWS;
    for (int t = tid; t < ROWS * FI; t += NT) {
        int rr = t / FI, kk = t % FI;
        int row = row0 + rr;
        xs[rr][kk] = (row < N) ? h[(size_t)row * FI + kk] : 0.0f;
    }
    __syncthreads();
    const int row = row0 + r;
    if (row >= N) return;
    float acc = 0.0f;
#pragma unroll
    for (int k = 0; k < FI; ++k)
        acc = fmaf(xs[r][k], W[k * FO + j], acc);
    y[(size_t)row * FO + j] = dinv[row] * acc;
}

// ---------------- segment-swept aggregate, interleaved sublists ----------------
// One block per 64-node bucket. Thread (fp, ty) owns feature-pair fp of NPT
// nodes. Per segment, walks its NPT sublists in LOCKSTEP -- one edge from each
// per round, all gathers independent -> NPT loads in flight per lane (fixes
// R9's dependent short-loop stall) while keeping the seg sweep's L2 locality.
template<int F, bool RELU>
__global__ __launch_bounds__(256)
void k_agg_seg(const int* __restrict__ rptr, const unsigned* __restrict__ csr,
               const __hip_bfloat16* __restrict__ y, const float* __restrict__ dinv,
               const float* __restrict__ bias, float* __restrict__ out) {
    constexpr int LPN  = F / 2;             // lanes per node (32 or 16)
    constexpr int NPY  = 256 / LPN;         // node-threads (8 or 16)
    constexpr int NPT  = BUK_NODES / NPY;   // nodes per thread (8 or 4)
    const int fp = threadIdx.x;             // 0..LPN-1
    const int ty = threadIdx.y;             // 0..NPY-1
    const int b = blockIdx.x;
    const int base = b << BUK_SHIFT;
    const int rbase = b * RSTR;
    const unsigned* yw = (const unsigned*)y;

    auto load2 = [&](int s) -> float2 {
        unsigned u = yw[(size_t)s * LPN + fp];
        float2 v;
        v.x = __uint_as_float(u << 16);
        v.y = __uint_as_float(u & 0xffff0000u);
        return v;
    };

    float2 acc[NPT];
#pragma unroll
    for (int i = 0; i < NPT; ++i) { acc[i].x = 0.0f; acc[i].y = 0.0f; }

    for (int seg = 0; seg < NSEG; ++seg) {
        int j[NPT], j1[NPT];
        int rem = 0;
#pragma unroll
        for (int i = 0; i < NPT; ++i) {
            const int k = rbase + seg * BUK_NODES + (ty + NPY * i);
            j[i]  = rptr[k];
            j1[i] = rptr[k + 1];
            rem = max(rem, j1[i] - j[i]);
        }
        for (; rem > 0; --rem) {
            unsigned s[NPT];
            bool p[NPT];
#pragma unroll
            for (int i = 0; i < NPT; ++i) {
                p[i] = j[i] < j1[i];
                s[i] = p[i] ? csr[j[i]] : 0u;
            }
            float2 v[NPT];
#pragma unroll
            for (int i = 0; i < NPT; ++i)
                if (p[i]) v[i] = load2((int)s[i]);
#pragma unroll
            for (int i = 0; i < NPT; ++i)
                if (p[i]) { acc[i].x += v[i].x; acc[i].y += v[i].y; ++j[i]; }
        }
    }

    const float b0 = bias[2 * fp], b1 = bias[2 * fp + 1];
#pragma unroll
    for (int i = 0; i < NPT; ++i) {
        const int node = base + ty + NPY * i;
        if (node >= N) continue;
        float2 self = load2(node);
        const float di = dinv[node];
        float o0 = fmaf(di, acc[i].x + self.x, b0);
        float o1 = fmaf(di, acc[i].y + self.y, b1);
        if (RELU) { o0 = fmaxf(o0, 0.0f); o1 = fmaxf(o1, 0.0f); }
        float2 res; res.x = o0; res.y = o1;
        *(float2*)&out[(size_t)node * F + 2 * fp] = res;
    }
}

// ---------------- layer 3 aggregate + log_softmax (2 classes) ----------------
__global__ __launch_bounds__(256)
void k_final(const int* __restrict__ rptr, const unsigned* __restrict__ csr,
             const float* __restrict__ y, const float* __restrict__ dinv,
             const float* __restrict__ bias, float* __restrict__ out) {
    const int c = threadIdx.x;                       // class 0/1
    const int n = blockIdx.x * 128 + threadIdx.y;    // node
    float z = 0.0f;
    if (n < N) {
        const int b = n >> BUK_SHIFT;
        const int ld = n & (BUK_NODES - 1);
        const int rbase = b * RSTR;
        float acc = y[2 * n + c];
        for (int seg = 0; seg < NSEG; ++seg) {
            const int k = rbase + seg * BUK_NODES + ld;
            int j = rptr[k];
            const int j1 = rptr[k + 1];
            for (; j + 2 <= j1; j += 2) {
                int s0 = (int)csr[j], s1 = (int)csr[j + 1];
                acc += y[2 * s0 + c] + y[2 * s1 + c];
            }
            for (; j < j1; ++j) acc += y[2 * (int)csr[j] + c];
        }
        z = fmaf(dinv[n], acc, bias[c]);
    }
    float zo = __shfl_xor(z, 1);
    if (n < N) {
        float m = fmaxf(z, zo);
        float lse = m + logf(expf(z - m) + expf(zo - m));
        out[2 * n + c] = z - lse;
    }
}

extern "C" void kernel_launch(void* const* d_in, const int* in_sizes, int n_in,
                              void* d_out, int out_size, void* d_ws, size_t ws_size,
                              hipStream_t stream) {
    const float* x   = (const float*)d_in[0];
    const int*   ei  = (const int*)d_in[1];
    const float* W1  = (const float*)d_in[2];
    const float* b1  = (const float*)d_in[3];
    const float* W2  = (const float*)d_in[4];
    const float* b2  = (const float*)d_in[5];
    const float* W3  = (const float*)d_in[6];
    const float* b3  = (const float*)d_in[7];
    float* out = (float*)d_out;

    const int* src = ei;
    const int* dst = ei + E;

    // workspace layout
    char* p = (char*)d_ws;
    float*    dinv    = (float*)p;    p += (size_t)N * 4;
    int*      gcursor = (int*)p;      p += (size_t)NBUK * 4;
    int*      rptr    = (int*)p;      p += (size_t)NBUK * RSTR * 4;   // 2.8 MB
    unsigned* ebuf    = (unsigned*)p; p += (size_t)NBUK * CAP * 4;    // 16 MB
    char*     bufA    = p;            p += (size_t)N * 64 * 4;        // 25.6 MB
    char*     bufB    = p;            p += (size_t)N * 64 * 4;        // 25.6 MB

    __hip_bfloat16* y1 = (__hip_bfloat16*)bufA;     // N*64*2 B
    float*          h1 = (float*)bufB;              // N*64*4 B
    __hip_bfloat16* y2 = (__hip_bfloat16*)bufA;     // N*32*2 B (y1 dead)
    float*          h2 = (float*)(bufA + (size_t)N * H2 * 2);  // N*32*4 B
    float*          y3 = (float*)bufB;              // N*2*4 B (h1 dead)

    // ---- edge structure build ----
    k_initcur<<<(NBUK + 255) / 256, 256, 0, stream>>>(gcursor);
    k_mslice <<<MS_WGS, MS_TPB, 0, stream>>>(src, dst, gcursor, ebuf);
    k_build  <<<NBUK, 256, 0, stream>>>(gcursor, ebuf, rptr, dinv);

    // ---- layer 1: 128 -> 64 ----
    k_gemm_tile_bf<FIN, H1><<<(N + 63) / 64, 256, 0, stream>>>(x, W1, dinv, y1);
    k_agg_seg<H1, true><<<NBUK, dim3(32, 8), 0, stream>>>(rptr, ebuf, y1, dinv, b1, h1);

    // ---- layer 2: 64 -> 32 ----
    k_gemm_tile_bf<H1, H2><<<(N + 63) / 64, 256, 0, stream>>>(h1, W2, dinv, y2);
    k_agg_seg<H2, true><<<NBUK, dim3(16, 16), 0, stream>>>(rptr, ebuf, y2, dinv, b2, h2);

    // ---- layer 3: 32 -> 2 + log_softmax ----
    k_gemm_scale<H2, COUT, 128><<<(N + 127) / 128, dim3(COUT, 128), 0, stream>>>(h2, W3, dinv, y3);
    k_final<<<(N + 127) / 128, dim3(2, 128), 0, stream>>>(rptr, ebuf, y3, dinv, b3, out);
}

// Round 12
// 379.236 us; speedup vs baseline: 5.3224x; 1.8799x over previous
//
#include <hip/hip_runtime.h>
#include <hip/hip_bf16.h>
#include <math.h>

// Problem constants (from reference)
constexpr int N = 100000;    // nodes
constexpr int E = 3200000;   // edges
constexpr int FIN = 128, H1 = 64, H2 = 32, COUT = 2;

// Bucketing: 64 dst-nodes per bucket, fixed-capacity slices
constexpr int BUK_SHIFT = 6;
constexpr int BUK_NODES = 64;                          // 1 << BUK_SHIFT
constexpr int NBUK = (N + BUK_NODES - 1) / BUK_NODES;  // 1563
constexpr int CAP = 2560;             // slice capacity; mean fill 2048, sigma~45
// src segmentation: seg = src >> 14 (16384 rows = 2.1 MB of y1). Node lists are
// stored seg-sorted so the R7 flat loop sweeps segments in time implicitly.
constexpr int SEG_SHIFT = 14;
constexpr int NSEG = 7;
constexpr int KEYS = BUK_NODES * NSEG;                 // 448 (ld-major!)
constexpr int RP_STR = BUK_NODES + 1;                  // 65 rowptr slots per bucket

constexpr int MS_TPB = 1024;
constexpr int MS_EPT = 24;                             // edges per thread
constexpr int CHUNK = MS_TPB * MS_EPT;                 // 24576
constexpr int MS_WGS = (E + CHUNK - 1) / CHUNK;        // 131

// ---------------- init: gcursor[b] = b*CAP ----------------
__global__ void k_initcur(int* __restrict__ gcursor) {
    int i = blockIdx.x * blockDim.x + threadIdx.x;
    if (i < NBUK) gcursor[i] = i * CAP;
}

// ---------------- multisplit into fixed-capacity bucket slices ----------------
// packed entry: src (17 bits) | local_node (6 bits) << 17
__global__ __launch_bounds__(MS_TPB)
void k_mslice(const int* __restrict__ src, const int* __restrict__ dst,
              int* __restrict__ gcursor, unsigned* __restrict__ ebuf) {
    __shared__ int cnt[NBUK];
    __shared__ int base[NBUK];
    const int t = threadIdx.x;
    for (int i = t; i < NBUK; i += MS_TPB) cnt[i] = 0;
    __syncthreads();
    const int e0 = blockIdx.x * CHUNK;

    int rb[MS_EPT];
    unsigned rv[MS_EPT];
#pragma unroll
    for (int j = 0; j < MS_EPT; ++j) {
        int e = e0 + j * MS_TPB + t;
        if (e < E) {
            int d = dst[e];
            int b = d >> BUK_SHIFT;
            rb[j] = b;
            rv[j] = (unsigned)src[e] | ((unsigned)(d & (BUK_NODES - 1)) << 17);
            atomicAdd(&cnt[b], 1);
        } else {
            rb[j] = -1; rv[j] = 0;
        }
    }
    __syncthreads();
    for (int i = t; i < NBUK; i += MS_TPB) {
        int c = cnt[i];
        base[i] = c ? atomicAdd(&gcursor[i], c) : 0;
    }
    __syncthreads();
    for (int i = t; i < NBUK; i += MS_TPB) cnt[i] = 0;
    __syncthreads();
#pragma unroll
    for (int j = 0; j < MS_EPT; ++j) {
        int b = rb[j];
        if (b >= 0) {
            int r = atomicAdd(&cnt[b], 1);
            int p = base[b] + r;
            if (p < (b + 1) * CAP) ebuf[p] = rv[j];   // overflow guard (statistically impossible)
        }
    }
}

// ---------------- per-bucket build: counting-sort by (local_dst, seg) ----------------
// ld-major key => each node's list is contiguous AND seg-sorted within.
// Emits rp[b*65 + ld] = node list start, rp[b*65+64] = slice end; dinv.
__global__ __launch_bounds__(256)
void k_build(const int* __restrict__ gcursor, unsigned* __restrict__ ebuf,
             int* __restrict__ rp, float* __restrict__ dinv) {
    __shared__ unsigned ent[CAP];
    __shared__ int cnt[512];
    __shared__ int sa[512];
    __shared__ int sb[512];
    __shared__ int cur[512];
    const int b = blockIdx.x;
    const int t = threadIdx.x;
    int fill = gcursor[b] - b * CAP;
    if (fill > CAP) fill = CAP;
    const int gbase = b * CAP;

    cnt[t] = 0; cnt[t + 256] = 0;
    __syncthreads();
    for (int j = t; j < fill; j += 256) {
        unsigned v = ebuf[gbase + j];
        ent[j] = v;
        int key = (int)(v >> 17) * NSEG + (int)((v & 0x1FFFFu) >> SEG_SHIFT);
        atomicAdd(&cnt[key], 1);
    }
    __syncthreads();
    sa[t] = cnt[t]; sa[t + 256] = cnt[t + 256];
    __syncthreads();
    int* pin = sa; int* pout = sb;
    for (int off = 1; off < 512; off <<= 1) {
        pout[t]       = pin[t]       + ((t >= off)       ? pin[t - off]       : 0);
        pout[t + 256] = pin[t + 256] + ((t + 256 >= off) ? pin[t + 256 - off] : 0);
        __syncthreads();
        int* tmp = pin; pin = pout; pout = tmp;
    }
    {
        int ex0 = pin[t] - cnt[t];
        int ex1 = pin[t + 256] - cnt[t + 256];
        cur[t] = gbase + ex0;
        cur[t + 256] = gbase + ex1;
        // node list start = start of its first (seg=0) key
        if (t < KEYS && (t % NSEG) == 0)
            rp[b * RP_STR + t / NSEG] = gbase + ex0;
        int k2 = t + 256;
        if (k2 < KEYS && (k2 % NSEG) == 0)
            rp[b * RP_STR + k2 / NSEG] = gbase + ex1;
        if (t == 0) rp[b * RP_STR + BUK_NODES] = gbase + fill;   // sentinel
    }
    if (t < BUK_NODES) {
        int deg = 0;
#pragma unroll
        for (int s = 0; s < NSEG; ++s) deg += cnt[t * NSEG + s];
        int node = (b << BUK_SHIFT) + t;
        if (node < N) dinv[node] = rsqrtf((float)deg + 1.0f);  // self-loop included
    }
    __syncthreads();
    for (int j = t; j < fill; j += 256) {
        unsigned v = ent[j];
        int key = (int)(v >> 17) * NSEG + (int)((v & 0x1FFFFu) >> SEG_SHIFT);
        int p = atomicAdd(&cur[key], 1);
        ebuf[p] = v & 0x1FFFFu;   // sorted, plain src
    }
}

// ---------------- register-tiled GEMM + dinv scale, bf16 output ----------------
template<int FI, int FO>
__global__ __launch_bounds__(256)
void k_gemm_tile_bf(const float* __restrict__ h, const float* __restrict__ Wg,
                    const float* __restrict__ dinv, __hip_bfloat16* __restrict__ y) {
    constexpr int TX  = FO / 4;
    constexpr int TY  = 256 / TX;
    constexpr int RPT = 64 / TY;
    constexpr int XS  = 68;
    constexpr int KQ  = FI / 4;

    __shared__ float xsT[FI][XS];

    const int tid = threadIdx.x;
    const int tx = tid % TX;
    const int ty = tid / TX;
    const int row0 = blockIdx.x * 64;

    for (int idx = tid; idx < 64 * KQ; idx += 256) {
        int g   = idx / 8;
        int rlo = idx % 8;
        int k4  = g % KQ;
        int rhi = g / KQ;
        int r   = rlo + 8 * rhi;
        int row = row0 + r;
        float4 v = make_float4(0.f, 0.f, 0.f, 0.f);
        if (row < N) v = *(const float4*)(h + (size_t)row * FI + 4 * k4);
        xsT[4 * k4 + 0][r] = v.x;
        xsT[4 * k4 + 1][r] = v.y;
        xsT[4 * k4 + 2][r] = v.z;
        xsT[4 * k4 + 3][r] = v.w;
    }
    __syncthreads();

    float acc[RPT][4];
#pragma unroll
    for (int i = 0; i < RPT; ++i)
#pragma unroll
        for (int c = 0; c < 4; ++c) acc[i][c] = 0.0f;

#pragma unroll 4
    for (int k = 0; k < FI; ++k) {
        const float4 wv = *(const float4*)(Wg + (size_t)k * FO + 4 * tx);
        float xv[RPT];
        if constexpr (RPT == 4) {
            float4 t = *(const float4*)&xsT[k][4 * ty];
            xv[0] = t.x; xv[1] = t.y; xv[2] = t.z; xv[3] = t.w;
        } else {
            float2 t = *(const float2*)&xsT[k][2 * ty];
            xv[0] = t.x; xv[1] = t.y;
        }
#pragma unroll
        for (int i = 0; i < RPT; ++i) {
            acc[i][0] = fmaf(xv[i], wv.x, acc[i][0]);
            acc[i][1] = fmaf(xv[i], wv.y, acc[i][1]);
            acc[i][2] = fmaf(xv[i], wv.z, acc[i][2]);
            acc[i][3] = fmaf(xv[i], wv.w, acc[i][3]);
        }
    }

#pragma unroll
    for (int i = 0; i < RPT; ++i) {
        int row = row0 + ty * RPT + i;
        if (row >= N) continue;
        float di = dinv[row];
        auto cvt = [](float f) -> unsigned short {
            __hip_bfloat16 b = __float2bfloat16(f);
            return *reinterpret_cast<unsigned short*>(&b);
        };
        ushort4 pk;
        pk.x = cvt(di * acc[i][0]);
        pk.y = cvt(di * acc[i][1]);
        pk.z = cvt(di * acc[i][2]);
        pk.w = cvt(di * acc[i][3]);
        *(ushort4*)&y[(size_t)row * FO + 4 * tx] = pk;
    }
}

// ---------------- fused GEMM + dinv scale, fp32 output (layer 3, tiny) ----------------
template<int FI, int FO, int ROWS>
__global__ __launch_bounds__(FO * ROWS)
void k_gemm_scale(const float* __restrict__ h, const float* __restrict__ W,
                  const float* __restrict__ dinv, float* __restrict__ y) {
    __shared__ float xs[ROWS][FI];
    const int j = threadIdx.x;
    const int r = threadIdx.y;
    const int row0 = blockIdx.x * ROWS;
    const int tid = r * FO + j;
    constexpr int NT = FO * ROWS;
    for (int t = tid; t < ROWS * FI; t += NT) {
        int rr = t / FI, kk = t % FI;
        int row = row0 + rr;
        xs[rr][kk] = (row < N) ? h[(size_t)row * FI + kk] : 0.0f;
    }
    __syncthreads();
    const int row = row0 + r;
    if (row >= N) return;
    float acc = 0.0f;
#pragma unroll
    for (int k = 0; k < FI; ++k)
        acc = fmaf(xs[r][k], W[k * FO + j], acc);
    y[(size_t)row * FO + j] = dinv[row] * acc;
}

// ---------------- CSR aggregate (bf16 gather) + fused epilogue ----------------
// R7's proven flat loop; lists are seg-sorted so the walk sweeps y segments
// in time across all co-resident waves (implicit L2 locality, zero overhead).
template<int F, bool RELU>
__global__ __launch_bounds__(256)
void k_aggregate_bf(const int* __restrict__ rp, const unsigned* __restrict__ csr,
                    const __hip_bfloat16* __restrict__ y, const float* __restrict__ dinv,
                    const float* __restrict__ b, float* __restrict__ out) {
    constexpr int LPN = F / 2;         // lanes per node
    constexpr int NPB = 256 / LPN;     // nodes per block
    const int fp = threadIdx.x;        // feature-pair index
    const int n = blockIdx.x * NPB + threadIdx.y;
    if (n >= N) return;
    const unsigned* yw = (const unsigned*)y;

    auto load2 = [&](int s) -> float2 {
        unsigned u = yw[(size_t)s * LPN + fp];
        float2 v;
        v.x = __uint_as_float(u << 16);
        v.y = __uint_as_float(u & 0xffff0000u);
        return v;
    };

    const int rb = (n >> BUK_SHIFT) * RP_STR + (n & (BUK_NODES - 1));
    const int j0 = rp[rb], j1 = rp[rb + 1];
    float2 acc = load2(n);   // self-loop
    int j = j0;
    for (; j + 8 <= j1; j += 8) {   // unroll-8: 8 gathers in flight per lane
        int s0 = (int)csr[j],     s1 = (int)csr[j + 1], s2 = (int)csr[j + 2], s3 = (int)csr[j + 3];
        int s4 = (int)csr[j + 4], s5 = (int)csr[j + 5], s6 = (int)csr[j + 6], s7 = (int)csr[j + 7];
        float2 v0 = load2(s0), v1 = load2(s1), v2 = load2(s2), v3 = load2(s3);
        float2 v4 = load2(s4), v5 = load2(s5), v6 = load2(s6), v7 = load2(s7);
        acc.x += ((v0.x + v1.x) + (v2.x + v3.x)) + ((v4.x + v5.x) + (v6.x + v7.x));
        acc.y += ((v0.y + v1.y) + (v2.y + v3.y)) + ((v4.y + v5.y) + (v6.y + v7.y));
    }
    for (; j < j1; ++j) {
        float2 v = load2((int)csr[j]);
        acc.x += v.x; acc.y += v.y;
    }
    const float di = dinv[n];
    float o0 = fmaf(di, acc.x, b[2 * fp]);
    float o1 = fmaf(di, acc.y, b[2 * fp + 1]);
    if (RELU) { o0 = fmaxf(o0, 0.0f); o1 = fmaxf(o1, 0.0f); }
    float2 res; res.x = o0; res.y = o1;
    *(float2*)&out[(size_t)n * F + 2 * fp] = res;
}

// ---------------- layer 3 aggregate + log_softmax (2 classes) ----------------
__global__ __launch_bounds__(256)
void k_final(const int* __restrict__ rp, const unsigned* __restrict__ csr,
             const float* __restrict__ y, const float* __restrict__ dinv,
             const float* __restrict__ bias, float* __restrict__ out) {
    const int c = threadIdx.x;                       // class 0/1
    const int n = blockIdx.x * 128 + threadIdx.y;    // node
    float z = 0.0f;
    if (n < N) {
        const int rb = (n >> BUK_SHIFT) * RP_STR + (n & (BUK_NODES - 1));
        int j = rp[rb];
        const int j1 = rp[rb + 1];
        float acc = y[2 * n + c];
        for (; j + 4 <= j1; j += 4) {
            int s0 = (int)csr[j], s1 = (int)csr[j + 1], s2 = (int)csr[j + 2], s3 = (int)csr[j + 3];
            float a0 = y[2 * s0 + c], a1 = y[2 * s1 + c];
            float a2 = y[2 * s2 + c], a3 = y[2 * s3 + c];
            acc += (a0 + a1) + (a2 + a3);
        }
        for (; j < j1; ++j) acc += y[2 * (int)csr[j] + c];
        z = fmaf(dinv[n], acc, bias[c]);
    }
    float zo = __shfl_xor(z, 1);
    if (n < N) {
        float m = fmaxf(z, zo);
        float lse = m + logf(expf(z - m) + expf(zo - m));
        out[2 * n + c] = z - lse;
    }
}

extern "C" void kernel_launch(void* const* d_in, const int* in_sizes, int n_in,
                              void* d_out, int out_size, void* d_ws, size_t ws_size,
                              hipStream_t stream) {
    const float* x   = (const float*)d_in[0];
    const int*   ei  = (const int*)d_in[1];
    const float* W1  = (const float*)d_in[2];
    const float* b1  = (const float*)d_in[3];
    const float* W2  = (const float*)d_in[4];
    const float* b2  = (const float*)d_in[5];
    const float* W3  = (const float*)d_in[6];
    const float* b3  = (const float*)d_in[7];
    float* out = (float*)d_out;

    const int* src = ei;
    const int* dst = ei + E;

    // workspace layout
    char* p = (char*)d_ws;
    float*    dinv    = (float*)p;    p += (size_t)N * 4;
    int*      gcursor = (int*)p;      p += (size_t)NBUK * 4;
    int*      rp      = (int*)p;      p += (size_t)NBUK * RP_STR * 4;  // 406 KB
    unsigned* ebuf    = (unsigned*)p; p += (size_t)NBUK * CAP * 4;     // 16 MB
    char*     bufA    = p;            p += (size_t)N * 64 * 4;         // 25.6 MB
    char*     bufB    = p;            p += (size_t)N * 64 * 4;         // 25.6 MB

    __hip_bfloat16* y1 = (__hip_bfloat16*)bufA;     // N*64*2 B
    float*          h1 = (float*)bufB;              // N*64*4 B
    __hip_bfloat16* y2 = (__hip_bfloat16*)bufA;     // N*32*2 B (y1 dead)
    float*          h2 = (float*)(bufA + (size_t)N * H2 * 2);  // N*32*4 B
    float*          y3 = (float*)bufB;              // N*2*4 B (h1 dead)

    // ---- edge structure build ----
    k_initcur<<<(NBUK + 255) / 256, 256, 0, stream>>>(gcursor);
    k_mslice <<<MS_WGS, MS_TPB, 0, stream>>>(src, dst, gcursor, ebuf);
    k_build  <<<NBUK, 256, 0, stream>>>(gcursor, ebuf, rp, dinv);

    // ---- layer 1: 128 -> 64 ----
    k_gemm_tile_bf<FIN, H1><<<(N + 63) / 64, 256, 0, stream>>>(x, W1, dinv, y1);
    k_aggregate_bf<H1, true><<<(N + 7) / 8, dim3(32, 8), 0, stream>>>(rp, ebuf, y1, dinv, b1, h1);

    // ---- layer 2: 64 -> 32 ----
    k_gemm_tile_bf<H1, H2><<<(N + 63) / 64, 256, 0, stream>>>(h1, W2, dinv, y2);
    k_aggregate_bf<H2, true><<<(N + 15) / 16, dim3(16, 16), 0, stream>>>(rp, ebuf, y2, dinv, b2, h2);

    // ---- layer 3: 32 -> 2 + log_softmax ----
    k_gemm_scale<H2, COUT, 128><<<(N + 127) / 128, dim3(COUT, 128), 0, stream>>>(h2, W3, dinv, y3);
    k_final<<<(N + 127) / 128, dim3(2, 128), 0, stream>>>(rp, ebuf, y3, dinv, b3, out);
}